// Round 1
// baseline (733.456 us; speedup 1.0000x reference)
//
#include <hip/hip_runtime.h>
#include <cstdint>
#include <cstddef>

#define N_NODES 50000
#define N_EDGES 800000
#define IN_CH   64
#define OC      128   // HEADS*OUT_CH
#define HEADS   4
#define CH      32    // OUT_CH

static inline int ceil_div(int a, int b){ return (a + b - 1) / b; }

__device__ __forceinline__ unsigned enc_f(float f){
  unsigned b = __float_as_uint(f);
  return (b & 0x80000000u) ? ~b : (b | 0x80000000u);
}
__device__ __forceinline__ float dec_f(unsigned u){
  unsigned b = (u & 0x80000000u) ? (u & 0x7FFFFFFFu) : ~u;
  return __uint_as_float(b);
}
__device__ __forceinline__ float lrelu(float x){ return x > 0.f ? x : 0.2f * x; }

// ---- K0: x_pos = x (float4 copy) ----
__global__ __launch_bounds__(256) void k_copy_x(const float* __restrict__ x,
                                                float* __restrict__ x_pos, int n4){
  int i = blockIdx.x * blockDim.x + threadIdx.x;
  if (i < n4) ((float4*)x_pos)[i] = ((const float4*)x)[i];
}

// ---- K1: x_pos[src[e]] += pe[edge_type[e]]  (wave per edge, lane = channel) ----
__global__ __launch_bounds__(256) void k_pe_scatter(const int* __restrict__ ei,
                                                    const int* __restrict__ et,
                                                    const float* __restrict__ pe,
                                                    float* __restrict__ x_pos){
  int t = blockIdx.x * blockDim.x + threadIdx.x;
  int e = t >> 6;
  if (e >= N_EDGES) return;
  int c = t & 63;
  int s  = ei[e];          // edge_index row 0
  int ty = et[e];
  atomicAdd(&x_pos[(size_t)s * IN_CH + c], pe[ty * IN_CH + c]);
}

// ---- K2: xl = x_pos @ W   (32-row tile per block, W + x tile in LDS) ----
#define GROWS 32
__global__ __launch_bounds__(256) void k_gemm(const float* __restrict__ xp,
                                              const float* __restrict__ W,
                                              float* __restrict__ xl){
  __shared__ float sW[IN_CH * OC];      // 32 KB
  __shared__ float sX[GROWS * IN_CH];   // 8 KB
  int tid = threadIdx.x;
  for (int i = tid; i < IN_CH * OC / 4; i += 256)
    ((float4*)sW)[i] = ((const float4*)W)[i];
  int row0 = blockIdx.x * GROWS;
  for (int i = tid; i < GROWS * IN_CH / 4; i += 256){
    int r = i >> 4;  // 16 float4 per row
    float4 v = make_float4(0.f, 0.f, 0.f, 0.f);
    if (row0 + r < N_NODES)
      v = ((const float4*)(xp + (size_t)row0 * IN_CH))[i];
    ((float4*)sX)[i] = v;
  }
  __syncthreads();
  int c  = tid & 127;
  int rb = tid >> 7;
  for (int k = 0; k < GROWS / 2; ++k){
    int r = rb + 2 * k;
    float acc = 0.f;
    #pragma unroll
    for (int i = 0; i < IN_CH; ++i)
      acc += sX[r * IN_CH + i] * sW[i * OC + c];
    if (row0 + r < N_NODES)
      xl[(size_t)(row0 + r) * OC + c] = acc;
  }
}

// ---- K3: a_src/a_dst per (node, head) ----
__global__ __launch_bounds__(256) void k_attn_dots(const float* __restrict__ xl,
                                                   const float* __restrict__ as,
                                                   const float* __restrict__ ad,
                                                   float* __restrict__ a_src,
                                                   float* __restrict__ a_dst){
  int i = blockIdx.x * blockDim.x + threadIdx.x;  // over N*HEADS
  if (i >= N_NODES * HEADS) return;
  int h = i & 3, n = i >> 2;
  const float* row = xl + (size_t)n * OC + h * CH;
  float s = 0.f, d = 0.f;
  #pragma unroll
  for (int c = 0; c < CH; ++c){
    float v = row[c];
    s += v * as[h * CH + c];
    d += v * ad[h * CH + c];
  }
  a_src[i] = s; a_dst[i] = d;
}

// ---- K4: init amax (enc 0) and denom (0) ----
__global__ __launch_bounds__(256) void k_init_md(unsigned* __restrict__ amax_u,
                                                 float* __restrict__ denom){
  int i = blockIdx.x * blockDim.x + threadIdx.x;
  if (i < N_NODES * HEADS){ amax_u[i] = 0u; denom[i] = 0.f; }
}

// ---- K5: segment max over edges ----
__global__ __launch_bounds__(256) void k_edge_max(const int* __restrict__ ei,
                                                  const float* __restrict__ a_src,
                                                  const float* __restrict__ a_dst,
                                                  unsigned* __restrict__ amax_u){
  int i = blockIdx.x * blockDim.x + threadIdx.x;  // over E*HEADS
  if (i >= N_EDGES * HEADS) return;
  int h = i & 3, e = i >> 2;
  int s = ei[e], d = ei[N_EDGES + e];
  float al = lrelu(a_src[s * 4 + h] + a_dst[d * 4 + h]);
  atomicMax(&amax_u[d * 4 + h], enc_f(al));
}
__global__ __launch_bounds__(256) void k_self_max(const float* __restrict__ a_src,
                                                  const float* __restrict__ a_dst,
                                                  unsigned* __restrict__ amax_u){
  int i = blockIdx.x * blockDim.x + threadIdx.x;  // over N*HEADS
  if (i >= N_NODES * HEADS) return;
  float al = lrelu(a_src[i] + a_dst[i]);
  atomicMax(&amax_u[i], enc_f(al));
}

// ---- K6: segment sum of exp ----
__global__ __launch_bounds__(256) void k_edge_denom(const int* __restrict__ ei,
                                                    const float* __restrict__ a_src,
                                                    const float* __restrict__ a_dst,
                                                    const unsigned* __restrict__ amax_u,
                                                    float* __restrict__ denom){
  int i = blockIdx.x * blockDim.x + threadIdx.x;  // over E*HEADS
  if (i >= N_EDGES * HEADS) return;
  int h = i & 3, e = i >> 2;
  int s = ei[e], d = ei[N_EDGES + e];
  float al = lrelu(a_src[s * 4 + h] + a_dst[d * 4 + h]);
  atomicAdd(&denom[d * 4 + h], expf(al - dec_f(amax_u[d * 4 + h])));
}
__global__ __launch_bounds__(256) void k_self_denom(const float* __restrict__ a_src,
                                                    const float* __restrict__ a_dst,
                                                    const unsigned* __restrict__ amax_u,
                                                    float* __restrict__ denom){
  int i = blockIdx.x * blockDim.x + threadIdx.x;
  if (i >= N_NODES * HEADS) return;
  float al = lrelu(a_src[i] + a_dst[i]);
  atomicAdd(&denom[i], expf(al - dec_f(amax_u[i])));
}

// ---- K7: init out with self-loop term (covers poison) ----
__global__ __launch_bounds__(256) void k_self_out(const float* __restrict__ a_src,
                                                  const float* __restrict__ a_dst,
                                                  const unsigned* __restrict__ amax_u,
                                                  const float* __restrict__ denom,
                                                  const float* __restrict__ xl,
                                                  float* __restrict__ out){
  int i = blockIdx.x * blockDim.x + threadIdx.x;  // over N*OC
  if (i >= N_NODES * OC) return;
  int hc = i & 127, n = i >> 7;
  int h = hc >> 5;
  int nh = n * 4 + h;
  float al = lrelu(a_src[nh] + a_dst[nh]);
  float coef = expf(al - dec_f(amax_u[nh])) / denom[nh];
  out[i] = coef * xl[i];
}

// ---- K8: edge aggregation (128 threads per edge) ----
__global__ __launch_bounds__(256) void k_edge_out(const int* __restrict__ ei,
                                                  const float* __restrict__ a_src,
                                                  const float* __restrict__ a_dst,
                                                  const unsigned* __restrict__ amax_u,
                                                  const float* __restrict__ denom,
                                                  const float* __restrict__ xl,
                                                  float* __restrict__ out){
  long long t = (long long)blockIdx.x * blockDim.x + threadIdx.x;  // over E*OC
  if (t >= (long long)N_EDGES * OC) return;
  int c = (int)(t & 127);
  int e = (int)(t >> 7);
  int s = ei[e], d = ei[N_EDGES + e];
  int h = c >> 5;
  float al = lrelu(a_src[s * 4 + h] + a_dst[d * 4 + h]);
  int dh = d * 4 + h;
  float coef = expf(al - dec_f(amax_u[dh])) / denom[dh];
  atomicAdd(&out[(size_t)d * OC + c], coef * xl[(size_t)s * OC + c]);
}

// ---- K9: out = elu(out + bias), in place ----
__global__ __launch_bounds__(256) void k_elu_bias(float* __restrict__ out,
                                                  const float* __restrict__ bias){
  int i = blockIdx.x * blockDim.x + threadIdx.x;  // over N*OC
  if (i >= N_NODES * OC) return;
  float v = out[i] + bias[i & 127];
  out[i] = v > 0.f ? v : expm1f(v);
}

extern "C" void kernel_launch(void* const* d_in, const int* in_sizes, int n_in,
                              void* d_out, int out_size, void* d_ws, size_t ws_size,
                              hipStream_t stream){
  const float* x     = (const float*)d_in[0];
  const int*   ei    = (const int*)d_in[1];   // [2, E]
  const int*   et    = (const int*)d_in[2];   // [E]
  const float* pe    = (const float*)d_in[3];
  const float* W     = (const float*)d_in[4];
  const float* att_s = (const float*)d_in[5];
  const float* att_d = (const float*)d_in[6];
  const float* bias  = (const float*)d_in[7];
  float* out = (float*)d_out;

  float* x_pos = (float*)d_ws;                          // N*64
  float* xl    = x_pos + (size_t)N_NODES * IN_CH;       // N*128
  float* a_src = xl + (size_t)N_NODES * OC;             // N*4
  float* a_dst = a_src + (size_t)N_NODES * HEADS;       // N*4
  unsigned* amax_u = (unsigned*)(a_dst + (size_t)N_NODES * HEADS);  // N*4
  float* denom = (float*)(amax_u + (size_t)N_NODES * HEADS);        // N*4

  const int B = 256;

  k_copy_x<<<ceil_div(N_NODES * IN_CH / 4, B), B, 0, stream>>>(x, x_pos, N_NODES * IN_CH / 4);
  k_pe_scatter<<<ceil_div(N_EDGES * 64, B), B, 0, stream>>>(ei, et, pe, x_pos);
  k_gemm<<<ceil_div(N_NODES, GROWS), B, 0, stream>>>(x_pos, W, xl);
  k_attn_dots<<<ceil_div(N_NODES * HEADS, B), B, 0, stream>>>(xl, att_s, att_d, a_src, a_dst);
  k_init_md<<<ceil_div(N_NODES * HEADS, B), B, 0, stream>>>(amax_u, denom);
  k_edge_max<<<ceil_div(N_EDGES * HEADS, B), B, 0, stream>>>(ei, a_src, a_dst, amax_u);
  k_self_max<<<ceil_div(N_NODES * HEADS, B), B, 0, stream>>>(a_src, a_dst, amax_u);
  k_edge_denom<<<ceil_div(N_EDGES * HEADS, B), B, 0, stream>>>(ei, a_src, a_dst, amax_u, denom);
  k_self_denom<<<ceil_div(N_NODES * HEADS, B), B, 0, stream>>>(a_src, a_dst, amax_u, denom);
  k_self_out<<<ceil_div(N_NODES * OC, B), B, 0, stream>>>(a_src, a_dst, amax_u, denom, xl, out);
  {
    long long tot = (long long)N_EDGES * OC;
    int blocks = (int)((tot + B - 1) / B);
    k_edge_out<<<blocks, B, 0, stream>>>(ei, a_src, a_dst, amax_u, denom, xl, out);
  }
  k_elu_bias<<<ceil_div(N_NODES * OC, B), B, 0, stream>>>(out, bias);
}

// Round 2
// 696.475 us; speedup vs baseline: 1.0531x; 1.0531x over previous
//
#include <hip/hip_runtime.h>
#include <cstdint>
#include <cstddef>

#define N_NODES 50000
#define N_EDGES 800000
#define IN_CH   64
#define OC      128   // HEADS*OUT_CH
#define HEADS   4
#define CH      32    // OUT_CH

static inline int ceil_div(int a, int b){ return (a + b - 1) / b; }

__device__ __forceinline__ float lrelu(float x){ return x > 0.f ? x : 0.2f * x; }

// ---- CSR build: histogram ----
__global__ __launch_bounds__(256) void k_hist(const int* __restrict__ ei,
                                              int* __restrict__ cnt_src,
                                              int* __restrict__ cnt_dst){
  int e = blockIdx.x * blockDim.x + threadIdx.x;
  if (e >= N_EDGES) return;
  atomicAdd(&cnt_src[ei[e]], 1);
  atomicAdd(&cnt_dst[ei[N_EDGES + e]], 1);
}

// ---- CSR build: exclusive scan (one block per array; blockIdx selects) ----
__global__ __launch_bounds__(256) void k_scan(const int* __restrict__ cnt_src,
                                              const int* __restrict__ cnt_dst,
                                              int* __restrict__ row_src,
                                              int* __restrict__ row_dst,
                                              int* __restrict__ cur_src,
                                              int* __restrict__ cur_dst){
  const int* cnt = blockIdx.x == 0 ? cnt_src : cnt_dst;
  int* row = blockIdx.x == 0 ? row_src : row_dst;
  int* cur = blockIdx.x == 0 ? cur_src : cur_dst;
  __shared__ int buf[256];
  __shared__ int carry;
  int tid = threadIdx.x;
  if (tid == 0){ carry = 0; row[0] = 0; }
  __syncthreads();
  for (int base = 0; base < N_NODES; base += 256){
    int i = base + tid;
    int v = (i < N_NODES) ? cnt[i] : 0;
    buf[tid] = v;
    __syncthreads();
    #pragma unroll
    for (int off = 1; off < 256; off <<= 1){
      int t = (tid >= off) ? buf[tid - off] : 0;
      __syncthreads();
      buf[tid] += t;
      __syncthreads();
    }
    int incl = buf[tid];
    int base_off = carry;
    __syncthreads();
    if (tid == 255) carry = base_off + incl;
    if (i < N_NODES){
      row[i + 1] = base_off + incl;
      cur[i] = base_off + incl - v;
    }
    __syncthreads();
  }
}

// ---- CSR build: scatter edge ids ----
__global__ __launch_bounds__(256) void k_scatter(const int* __restrict__ ei,
                                                 int* __restrict__ cur_src,
                                                 int* __restrict__ cur_dst,
                                                 int* __restrict__ lst_src,
                                                 int* __restrict__ lst_dst){
  int e = blockIdx.x * blockDim.x + threadIdx.x;
  if (e >= N_EDGES) return;
  int p = atomicAdd(&cur_src[ei[e]], 1);
  lst_src[p] = e;
  int q = atomicAdd(&cur_dst[ei[N_EDGES + e]], 1);
  lst_dst[q] = e;
}

// ---- x_pos[n] = x[n] + sum over outgoing edges pe[edge_type] (wave per node) ----
__global__ __launch_bounds__(256) void k_pe_gather(const float* __restrict__ x,
                                                   const int* __restrict__ et,
                                                   const float* __restrict__ pe,
                                                   const int* __restrict__ row_src,
                                                   const int* __restrict__ lst_src,
                                                   float* __restrict__ x_pos){
  int w = (blockIdx.x * blockDim.x + threadIdx.x) >> 6;  // wave id = node
  if (w >= N_NODES) return;
  int c = threadIdx.x & 63;
  float acc = x[(size_t)w * IN_CH + c];
  int k0 = row_src[w], k1 = row_src[w + 1];
  for (int k = k0; k < k1; ++k){
    int t = et[lst_src[k]];
    acc += pe[t * IN_CH + c];
  }
  x_pos[(size_t)w * IN_CH + c] = acc;
}

// ---- xl = x_pos @ W  (32-row tile per block) ----
#define GROWS 32
__global__ __launch_bounds__(256) void k_gemm(const float* __restrict__ xp,
                                              const float* __restrict__ W,
                                              float* __restrict__ xl){
  __shared__ float sW[IN_CH * OC];      // 32 KB
  __shared__ float sX[GROWS * IN_CH];   // 8 KB
  int tid = threadIdx.x;
  for (int i = tid; i < IN_CH * OC / 4; i += 256)
    ((float4*)sW)[i] = ((const float4*)W)[i];
  int row0 = blockIdx.x * GROWS;
  for (int i = tid; i < GROWS * IN_CH / 4; i += 256){
    int r = i >> 4;
    float4 v = make_float4(0.f, 0.f, 0.f, 0.f);
    if (row0 + r < N_NODES)
      v = ((const float4*)(xp + (size_t)row0 * IN_CH))[i];
    ((float4*)sX)[i] = v;
  }
  __syncthreads();
  int c  = tid & 127;
  int rb = tid >> 7;
  for (int k = 0; k < GROWS / 2; ++k){
    int r = rb + 2 * k;
    float acc = 0.f;
    #pragma unroll
    for (int i = 0; i < IN_CH; ++i)
      acc += sX[r * IN_CH + i] * sW[i * OC + c];
    if (row0 + r < N_NODES)
      xl[(size_t)(row0 + r) * OC + c] = acc;
  }
}

// ---- a_src/a_dst per (node, head) ----
__global__ __launch_bounds__(256) void k_attn_dots(const float* __restrict__ xl,
                                                   const float* __restrict__ as,
                                                   const float* __restrict__ ad,
                                                   float* __restrict__ a_src,
                                                   float* __restrict__ a_dst){
  int i = blockIdx.x * blockDim.x + threadIdx.x;
  if (i >= N_NODES * HEADS) return;
  int h = i & 3, n = i >> 2;
  const float* row = xl + (size_t)n * OC + h * CH;
  float s = 0.f, d = 0.f;
  #pragma unroll
  for (int c = 0; c < CH; ++c){
    float v = row[c];
    s += v * as[h * CH + c];
    d += v * ad[h * CH + c];
  }
  a_src[i] = s; a_dst[i] = d;
}

// ---- fused: online segment-softmax + aggregate + bias + ELU (wave per node) ----
__global__ __launch_bounds__(256) void k_aggregate(const int* __restrict__ ei,
                                                   const int* __restrict__ row_dst,
                                                   const int* __restrict__ lst_dst,
                                                   const float* __restrict__ a_src,
                                                   const float* __restrict__ a_dst,
                                                   const float* __restrict__ xl,
                                                   const float* __restrict__ bias,
                                                   float* __restrict__ out){
  int n = (blockIdx.x * blockDim.x + threadIdx.x) >> 6;  // wave id = node
  if (n >= N_NODES) return;
  int c = threadIdx.x & 63;        // channel 0..63; also handles c+64
  int h0 = c >> 5;                 // head 0/1
  int h1 = 2 + h0;                 // head 2/3
  float ad0 = a_dst[n * 4 + h0];
  float ad1 = a_dst[n * 4 + h1];

  // self loop init: coef numerator exp(al-m)=1
  float m0 = lrelu(a_src[n * 4 + h0] + ad0);
  float m1 = lrelu(a_src[n * 4 + h1] + ad1);
  float l0 = 1.f, l1 = 1.f;
  float acc0 = xl[(size_t)n * OC + c];
  float acc1 = xl[(size_t)n * OC + 64 + c];

  int k0 = row_dst[n], k1 = row_dst[n + 1];
  for (int k = k0; k < k1; ++k){
    int e = lst_dst[k];
    int s = ei[e];
    float v0 = xl[(size_t)s * OC + c];
    float v1 = xl[(size_t)s * OC + 64 + c];
    float al0 = lrelu(a_src[s * 4 + h0] + ad0);
    float al1 = lrelu(a_src[s * 4 + h1] + ad1);
    if (al0 > m0){
      float f = __expf(m0 - al0);
      l0 *= f; acc0 *= f; m0 = al0;
    }
    float w0 = __expf(al0 - m0);
    l0 += w0; acc0 += w0 * v0;
    if (al1 > m1){
      float f = __expf(m1 - al1);
      l1 *= f; acc1 *= f; m1 = al1;
    }
    float w1 = __expf(al1 - m1);
    l1 += w1; acc1 += w1 * v1;
  }
  float r0 = acc0 / l0 + bias[c];
  float r1 = acc1 / l1 + bias[64 + c];
  out[(size_t)n * OC + c]      = r0 > 0.f ? r0 : expm1f(r0);
  out[(size_t)n * OC + 64 + c] = r1 > 0.f ? r1 : expm1f(r1);
}

extern "C" void kernel_launch(void* const* d_in, const int* in_sizes, int n_in,
                              void* d_out, int out_size, void* d_ws, size_t ws_size,
                              hipStream_t stream){
  const float* x     = (const float*)d_in[0];
  const int*   ei    = (const int*)d_in[1];   // [2, E]
  const int*   et    = (const int*)d_in[2];   // [E]
  const float* pe    = (const float*)d_in[3];
  const float* W     = (const float*)d_in[4];
  const float* att_s = (const float*)d_in[5];
  const float* att_d = (const float*)d_in[6];
  const float* bias  = (const float*)d_in[7];
  float* out = (float*)d_out;

  // workspace carve-up
  float* x_pos = (float*)d_ws;                               // N*64
  float* xl    = x_pos + (size_t)N_NODES * IN_CH;            // N*128
  float* a_src = xl + (size_t)N_NODES * OC;                  // N*4
  float* a_dst = a_src + (size_t)N_NODES * HEADS;            // N*4
  int* cnt_src = (int*)(a_dst + (size_t)N_NODES * HEADS);    // N
  int* cnt_dst = cnt_src + N_NODES;                          // N
  int* row_src = cnt_dst + N_NODES;                          // N+1
  int* row_dst = row_src + (N_NODES + 1);                    // N+1
  int* cur_src = row_dst + (N_NODES + 1);                    // N
  int* cur_dst = cur_src + N_NODES;                          // N
  int* lst_src = cur_dst + N_NODES;                          // E
  int* lst_dst = lst_src + N_EDGES;                          // E

  const int B = 256;

  hipMemsetAsync(cnt_src, 0, 2 * N_NODES * sizeof(int), stream);
  k_hist<<<ceil_div(N_EDGES, B), B, 0, stream>>>(ei, cnt_src, cnt_dst);
  k_scan<<<2, B, 0, stream>>>(cnt_src, cnt_dst, row_src, row_dst, cur_src, cur_dst);
  k_scatter<<<ceil_div(N_EDGES, B), B, 0, stream>>>(ei, cur_src, cur_dst, lst_src, lst_dst);
  k_pe_gather<<<ceil_div(N_NODES * 64, B), B, 0, stream>>>(x, et, pe, row_src, lst_src, x_pos);
  k_gemm<<<ceil_div(N_NODES, GROWS), B, 0, stream>>>(x_pos, W, xl);
  k_attn_dots<<<ceil_div(N_NODES * HEADS, B), B, 0, stream>>>(xl, att_s, att_d, a_src, a_dst);
  k_aggregate<<<ceil_div(N_NODES * 64, B), B, 0, stream>>>(ei, row_dst, lst_dst, a_src, a_dst, xl, bias, out);
}

// Round 3
// 407.429 us; speedup vs baseline: 1.8002x; 1.7094x over previous
//
#include <hip/hip_runtime.h>
#include <cstdint>
#include <cstddef>

#define N_NODES 50000
#define N_EDGES 800000
#define IN_CH   64
#define OC      128   // HEADS*OUT_CH
#define HEADS   4
#define CH      32    // OUT_CH

#define SCAN_ITEMS  2048                      // per block: 256 threads x 8
#define SCAN_BLOCKS ((N_NODES + SCAN_ITEMS - 1) / SCAN_ITEMS)  // 25

static inline int ceil_div(int a, int b){ return (a + b - 1) / b; }

__device__ __forceinline__ float lrelu(float x){ return x > 0.f ? x : 0.2f * x; }

// ---- CSR build: histogram ----
__global__ __launch_bounds__(256) void k_hist(const int* __restrict__ ei,
                                              int* __restrict__ cnt_src,
                                              int* __restrict__ cnt_dst){
  int e = blockIdx.x * blockDim.x + threadIdx.x;
  if (e >= N_EDGES) return;
  atomicAdd(&cnt_src[ei[e]], 1);
  atomicAdd(&cnt_dst[ei[N_EDGES + e]], 1);
}

// ---- scan phase 1: per-block partial sums (grid = 2*SCAN_BLOCKS) ----
__global__ __launch_bounds__(256) void k_scan1(const int* __restrict__ cnt_src,
                                               const int* __restrict__ cnt_dst,
                                               int* __restrict__ bsum){
  int arr = blockIdx.x / SCAN_BLOCKS;
  int blk = blockIdx.x % SCAN_BLOCKS;
  const int* cnt = arr ? cnt_dst : cnt_src;
  int tid = threadIdx.x;
  int base = blk * SCAN_ITEMS;
  int s = 0;
  #pragma unroll
  for (int j = 0; j < 8; ++j){
    int i = base + j * 256 + tid;
    if (i < N_NODES) s += cnt[i];
  }
  __shared__ int sbuf[256];
  sbuf[tid] = s; __syncthreads();
  for (int off = 128; off > 0; off >>= 1){
    if (tid < off) sbuf[tid] += sbuf[tid + off];
    __syncthreads();
  }
  if (tid == 0) bsum[blockIdx.x] = sbuf[0];
}

// ---- scan phase 2: local scan + block offset, write row (excl at i+1) and cur ----
__global__ __launch_bounds__(256) void k_scan2(const int* __restrict__ cnt_src,
                                               const int* __restrict__ cnt_dst,
                                               const int* __restrict__ bsum,
                                               int* __restrict__ row_src,
                                               int* __restrict__ row_dst,
                                               int* __restrict__ cur_src,
                                               int* __restrict__ cur_dst){
  int arr = blockIdx.x / SCAN_BLOCKS;
  int blk = blockIdx.x % SCAN_BLOCKS;
  const int* cnt = arr ? cnt_dst : cnt_src;
  int* row = arr ? row_dst : row_src;
  int* cur = arr ? cur_dst : cur_src;
  int tid = threadIdx.x;
  int base = blk * SCAN_ITEMS + tid * 8;

  __shared__ int sboff;
  if (tid == 0){
    int b = 0;
    for (int q = arr * SCAN_BLOCKS; q < arr * SCAN_BLOCKS + blk; ++q) b += bsum[q];
    sboff = b;
  }

  int v[8];
  if (base + 7 < N_NODES){
    int4 a = *(const int4*)(cnt + base);
    int4 b4 = *(const int4*)(cnt + base + 4);
    v[0]=a.x; v[1]=a.y; v[2]=a.z; v[3]=a.w;
    v[4]=b4.x; v[5]=b4.y; v[6]=b4.z; v[7]=b4.w;
  } else {
    #pragma unroll
    for (int j = 0; j < 8; ++j){
      int i = base + j;
      v[j] = (i < N_NODES) ? cnt[i] : 0;
    }
  }
  int pre[8]; int run = 0;
  #pragma unroll
  for (int j = 0; j < 8; ++j){ pre[j] = run; run += v[j]; }

  __shared__ int sbuf[256];
  sbuf[tid] = run; __syncthreads();
  for (int off = 1; off < 256; off <<= 1){
    int t = (tid >= off) ? sbuf[tid - off] : 0;
    __syncthreads();
    sbuf[tid] += t;
    __syncthreads();
  }
  int toff = sbuf[tid] - run;           // exclusive thread offset
  int boff = sboff;
  #pragma unroll
  for (int j = 0; j < 8; ++j){
    int i = base + j;
    if (i < N_NODES){
      int excl = boff + toff + pre[j];
      cur[i] = excl;
      row[i + 1] = excl + v[j];
    }
  }
  if (blockIdx.x == 0 && tid == 0){ row_src[0] = 0; row_dst[0] = 0; }
}

// ---- CSR build: scatter payloads (et into src-lists, src-id into dst-lists) ----
__global__ __launch_bounds__(256) void k_scatter(const int* __restrict__ ei,
                                                 const int* __restrict__ et,
                                                 int* __restrict__ cur_src,
                                                 int* __restrict__ cur_dst,
                                                 int* __restrict__ lst_src,
                                                 int* __restrict__ lst_dst){
  int e = blockIdx.x * blockDim.x + threadIdx.x;
  if (e >= N_EDGES) return;
  int s = ei[e], d = ei[N_EDGES + e];
  int p = atomicAdd(&cur_src[s], 1);
  lst_src[p] = et[e];
  int q = atomicAdd(&cur_dst[d], 1);
  lst_dst[q] = s;
}

// ---- x_pos[n] = x[n] + sum_{outgoing e} pe[type(e)]  (wave per node) ----
__global__ __launch_bounds__(256) void k_pe_gather(const float* __restrict__ x,
                                                   const float* __restrict__ pe,
                                                   const int* __restrict__ row_src,
                                                   const int* __restrict__ lst_src,
                                                   float* __restrict__ x_pos){
  int w = (blockIdx.x * blockDim.x + threadIdx.x) >> 6;
  if (w >= N_NODES) return;
  int c = threadIdx.x & 63;
  float acc = x[(size_t)w * IN_CH + c];
  int k0 = row_src[w], k1 = row_src[w + 1];
  for (int k = k0; k < k1; ++k){
    int t = lst_src[k];
    acc += pe[t * IN_CH + c];
  }
  x_pos[(size_t)w * IN_CH + c] = acc;
}

// ---- xl = x_pos @ W  (32-row tile per block) ----
#define GROWS 32
__global__ __launch_bounds__(256) void k_gemm(const float* __restrict__ xp,
                                              const float* __restrict__ W,
                                              float* __restrict__ xl){
  __shared__ float sW[IN_CH * OC];      // 32 KB
  __shared__ float sX[GROWS * IN_CH];   // 8 KB
  int tid = threadIdx.x;
  for (int i = tid; i < IN_CH * OC / 4; i += 256)
    ((float4*)sW)[i] = ((const float4*)W)[i];
  int row0 = blockIdx.x * GROWS;
  for (int i = tid; i < GROWS * IN_CH / 4; i += 256){
    int r = i >> 4;
    float4 v = make_float4(0.f, 0.f, 0.f, 0.f);
    if (row0 + r < N_NODES)
      v = ((const float4*)(xp + (size_t)row0 * IN_CH))[i];
    ((float4*)sX)[i] = v;
  }
  __syncthreads();
  int c  = tid & 127;
  int rb = tid >> 7;
  for (int k = 0; k < GROWS / 2; ++k){
    int r = rb + 2 * k;
    float acc = 0.f;
    #pragma unroll
    for (int i = 0; i < IN_CH; ++i)
      acc += sX[r * IN_CH + i] * sW[i * OC + c];
    if (row0 + r < N_NODES)
      xl[(size_t)(row0 + r) * OC + c] = acc;
  }
}

// ---- a_src/a_dst per (node, head) ----
__global__ __launch_bounds__(256) void k_attn_dots(const float* __restrict__ xl,
                                                   const float* __restrict__ as,
                                                   const float* __restrict__ ad,
                                                   float* __restrict__ a_src,
                                                   float* __restrict__ a_dst){
  int i = blockIdx.x * blockDim.x + threadIdx.x;
  if (i >= N_NODES * HEADS) return;
  int h = i & 3, n = i >> 2;
  const float* row = xl + (size_t)n * OC + h * CH;
  float s = 0.f, d = 0.f;
  #pragma unroll
  for (int c = 0; c < CH; ++c){
    float v = row[c];
    s += v * as[h * CH + c];
    d += v * ad[h * CH + c];
  }
  a_src[i] = s; a_dst[i] = d;
}

// ---- fused: online segment-softmax + aggregate + bias + ELU (wave per node) ----
// lane l owns channels (2l, 2l+1); head h = l>>4.
__global__ __launch_bounds__(256) void k_aggregate(const int* __restrict__ row_dst,
                                                   const int* __restrict__ lst_dst,
                                                   const float* __restrict__ a_src,
                                                   const float* __restrict__ a_dst,
                                                   const float* __restrict__ xl,
                                                   const float* __restrict__ bias,
                                                   float* __restrict__ out){
  int n = (blockIdx.x * blockDim.x + threadIdx.x) >> 6;
  if (n >= N_NODES) return;
  int l = threadIdx.x & 63;
  int h = l >> 4;
  float ad = a_dst[n * 4 + h];

  // self loop init (numerator exp(al-m)=1)
  float m = lrelu(a_src[n * 4 + h] + ad);
  float lsum = 1.f;
  float2 acc = ((const float2*)(xl + (size_t)n * OC))[l];

  int k0 = row_dst[n], k1 = row_dst[n + 1];
  for (int k = k0; k < k1; ++k){
    int s = lst_dst[k];
    float2 v = ((const float2*)(xl + (size_t)s * OC))[l];
    float al = lrelu(a_src[s * 4 + h] + ad);
    if (al > m){
      float f = __expf(m - al);
      lsum *= f; acc.x *= f; acc.y *= f; m = al;
    }
    float w = __expf(al - m);
    lsum += w; acc.x += w * v.x; acc.y += w * v.y;
  }
  float2 b = ((const float2*)bias)[l];
  float r0 = acc.x / lsum + b.x;
  float r1 = acc.y / lsum + b.y;
  float2 o;
  o.x = r0 > 0.f ? r0 : expm1f(r0);
  o.y = r1 > 0.f ? r1 : expm1f(r1);
  ((float2*)(out + (size_t)n * OC))[l] = o;
}

extern "C" void kernel_launch(void* const* d_in, const int* in_sizes, int n_in,
                              void* d_out, int out_size, void* d_ws, size_t ws_size,
                              hipStream_t stream){
  const float* x     = (const float*)d_in[0];
  const int*   ei    = (const int*)d_in[1];   // [2, E]
  const int*   et    = (const int*)d_in[2];   // [E]
  const float* pe    = (const float*)d_in[3];
  const float* W     = (const float*)d_in[4];
  const float* att_s = (const float*)d_in[5];
  const float* att_d = (const float*)d_in[6];
  const float* bias  = (const float*)d_in[7];
  float* out = (float*)d_out;

  // workspace carve-up
  float* x_pos = (float*)d_ws;                               // N*64
  float* xl    = x_pos + (size_t)N_NODES * IN_CH;            // N*128
  float* a_src = xl + (size_t)N_NODES * OC;                  // N*4
  float* a_dst = a_src + (size_t)N_NODES * HEADS;            // N*4
  int* cnt_src = (int*)(a_dst + (size_t)N_NODES * HEADS);    // N
  int* cnt_dst = cnt_src + N_NODES;                          // N
  int* row_src = cnt_dst + N_NODES;                          // N+1
  int* row_dst = row_src + (N_NODES + 1);                    // N+1
  int* cur_src = row_dst + (N_NODES + 1);                    // N
  int* cur_dst = cur_src + N_NODES;                          // N
  int* bsum    = cur_dst + N_NODES;                          // 64 (pad)
  int* lst_src = bsum + 64;                                  // E
  int* lst_dst = lst_src + N_EDGES;                          // E

  const int B = 256;

  hipMemsetAsync(cnt_src, 0, 2 * N_NODES * sizeof(int), stream);
  k_hist<<<ceil_div(N_EDGES, B), B, 0, stream>>>(ei, cnt_src, cnt_dst);
  k_scan1<<<2 * SCAN_BLOCKS, B, 0, stream>>>(cnt_src, cnt_dst, bsum);
  k_scan2<<<2 * SCAN_BLOCKS, B, 0, stream>>>(cnt_src, cnt_dst, bsum,
                                             row_src, row_dst, cur_src, cur_dst);
  k_scatter<<<ceil_div(N_EDGES, B), B, 0, stream>>>(ei, et, cur_src, cur_dst, lst_src, lst_dst);
  k_pe_gather<<<ceil_div(N_NODES * 64, B), B, 0, stream>>>(x, pe, row_src, lst_src, x_pos);
  k_gemm<<<ceil_div(N_NODES, GROWS), B, 0, stream>>>(x_pos, W, xl);
  k_attn_dots<<<ceil_div(N_NODES * HEADS, B), B, 0, stream>>>(xl, att_s, att_d, a_src, a_dst);
  k_aggregate<<<ceil_div(N_NODES * 64, B), B, 0, stream>>>(row_dst, lst_dst, a_src, a_dst, xl, bias, out);
}

// Round 4
// 293.747 us; speedup vs baseline: 2.4969x; 1.3870x over previous
//
#include <hip/hip_runtime.h>
#include <cstdint>
#include <cstddef>

#define N_NODES 50000
#define N_EDGES 800000
#define IN_CH   64
#define OC      128   // HEADS*OUT_CH
#define HEADS   4
#define CH      32    // OUT_CH

#define SCAN_ITEMS  2048                      // per block: 256 threads x 8
#define SCAN_BLOCKS ((N_NODES + SCAN_ITEMS - 1) / SCAN_ITEMS)  // 25

static inline int ceil_div(int a, int b){ return (a + b - 1) / b; }

__device__ __forceinline__ float lrelu(float x){ return x > 0.f ? x : 0.2f * x; }

// ---- histogram: dst-degree counts + packed (node,type) counts ----
// cnt_nt[n*32 + t/2]: low u16 = count of type 2j, high u16 = count of type 2j+1
__global__ __launch_bounds__(256) void k_hist2(const int* __restrict__ ei,
                                               const int* __restrict__ et,
                                               int* __restrict__ cnt_dst,
                                               unsigned* __restrict__ cnt_nt){
  int e = blockIdx.x * blockDim.x + threadIdx.x;
  if (e >= N_EDGES) return;
  int s = ei[e], d = ei[N_EDGES + e], t = et[e];
  atomicAdd(&cnt_dst[d], 1);
  atomicAdd(&cnt_nt[(size_t)s * 32 + (t >> 1)], (t & 1) ? 0x10000u : 1u);
}

// ---- scan phase 1: per-block partial sums over cnt_dst ----
__global__ __launch_bounds__(256) void k_scan1(const int* __restrict__ cnt,
                                               int* __restrict__ bsum){
  int blk = blockIdx.x, tid = threadIdx.x;
  int base = blk * SCAN_ITEMS;
  int s = 0;
  #pragma unroll
  for (int j = 0; j < 8; ++j){
    int i = base + j * 256 + tid;
    if (i < N_NODES) s += cnt[i];
  }
  __shared__ int sbuf[256];
  sbuf[tid] = s; __syncthreads();
  for (int off = 128; off > 0; off >>= 1){
    if (tid < off) sbuf[tid] += sbuf[tid + off];
    __syncthreads();
  }
  if (tid == 0) bsum[blk] = sbuf[0];
}

// ---- scan phase 2: local scan + block offset -> row_dst / cur_dst ----
__global__ __launch_bounds__(256) void k_scan2(const int* __restrict__ cnt,
                                               const int* __restrict__ bsum,
                                               int* __restrict__ row,
                                               int* __restrict__ cur){
  int blk = blockIdx.x, tid = threadIdx.x;
  int base = blk * SCAN_ITEMS + tid * 8;

  __shared__ int sboff;
  if (tid == 0){
    int b = 0;
    for (int q = 0; q < blk; ++q) b += bsum[q];
    sboff = b;
  }

  int v[8];
  if (base + 7 < N_NODES){
    int4 a = *(const int4*)(cnt + base);
    int4 b4 = *(const int4*)(cnt + base + 4);
    v[0]=a.x; v[1]=a.y; v[2]=a.z; v[3]=a.w;
    v[4]=b4.x; v[5]=b4.y; v[6]=b4.z; v[7]=b4.w;
  } else {
    #pragma unroll
    for (int j = 0; j < 8; ++j){
      int i = base + j;
      v[j] = (i < N_NODES) ? cnt[i] : 0;
    }
  }
  int pre[8]; int run = 0;
  #pragma unroll
  for (int j = 0; j < 8; ++j){ pre[j] = run; run += v[j]; }

  __shared__ int sbuf[256];
  sbuf[tid] = run; __syncthreads();
  for (int off = 1; off < 256; off <<= 1){
    int t = (tid >= off) ? sbuf[tid - off] : 0;
    __syncthreads();
    sbuf[tid] += t;
    __syncthreads();
  }
  int toff = sbuf[tid] - run;
  int boff = sboff;
  #pragma unroll
  for (int j = 0; j < 8; ++j){
    int i = base + j;
    if (i < N_NODES){
      int excl = boff + toff + pre[j];
      cur[i] = excl;
      row[i + 1] = excl + v[j];
    }
  }
  if (blk == 0 && tid == 0) row[0] = 0;
}

// ---- scatter src-id into dst-CSR list ----
__global__ __launch_bounds__(256) void k_scatter_dst(const int* __restrict__ ei,
                                                     int* __restrict__ cur_dst,
                                                     int* __restrict__ lst_dst){
  int e = blockIdx.x * blockDim.x + threadIdx.x;
  if (e >= N_EDGES) return;
  int s = ei[e], d = ei[N_EDGES + e];
  int q = atomicAdd(&cur_dst[d], 1);
  lst_dst[q] = s;
}

// ---- peW = pe @ W  (64x64 @ 64x128, one block) ----
__global__ __launch_bounds__(256) void k_prep(const float* __restrict__ pe,
                                              const float* __restrict__ W,
                                              float* __restrict__ peW){
  __shared__ float sPe[64 * 64];
  int tid = threadIdx.x;
  for (int i = tid; i < 64 * 64 / 4; i += 256)
    ((float4*)sPe)[i] = ((const float4*)pe)[i];
  __syncthreads();
  int c = tid & 127, rb = tid >> 7;
  for (int k = 0; k < 32; ++k){
    int t = rb + 2 * k;
    float a = 0.f;
    #pragma unroll
    for (int i = 0; i < 64; ++i) a += sPe[t * 64 + i] * W[i * 128 + c];
    peW[t * 128 + c] = a;
  }
}

// ---- fused GEMM: xl = x @ W + f32(cnt_nt) @ peW  (K-tiled, 32-row blocks) ----
#define GROWS 32
__global__ __launch_bounds__(256) void k_gemm_fused(const float* __restrict__ x,
                                                    const unsigned* __restrict__ cnt_nt,
                                                    const float* __restrict__ W,
                                                    const float* __restrict__ peW,
                                                    float* __restrict__ xl){
  __shared__ float sW[64 * 128];   // 32 KB
  __shared__ float sX[GROWS * 64]; // 8 KB
  int tid = threadIdx.x;
  int row0 = blockIdx.x * GROWS;
  int c = tid & 127, rb = tid >> 7;
  float acc[16];
  #pragma unroll
  for (int k = 0; k < 16; ++k) acc[k] = 0.f;

  // phase 0: x @ W
  for (int i = tid; i < 64 * 128 / 4; i += 256)
    ((float4*)sW)[i] = ((const float4*)W)[i];
  for (int i = tid; i < GROWS * 64 / 4; i += 256){
    int r = i >> 4;
    float4 v = make_float4(0.f, 0.f, 0.f, 0.f);
    if (row0 + r < N_NODES)
      v = ((const float4*)(x + (size_t)row0 * 64))[i];
    ((float4*)sX)[i] = v;
  }
  __syncthreads();
  #pragma unroll 1
  for (int k = 0; k < 16; ++k){
    int r = rb + 2 * k;
    float a = 0.f;
    #pragma unroll
    for (int i = 0; i < 64; ++i) a += sX[r * 64 + i] * sW[i * 128 + c];
    acc[k] += a;
  }
  __syncthreads();

  // phase 1: f32(cnt) @ peW
  for (int i = tid; i < 64 * 128 / 4; i += 256)
    ((float4*)sW)[i] = ((const float4*)peW)[i];
  for (int i = tid; i < GROWS * 32; i += 256){
    int r = i >> 5, j = i & 31;
    unsigned wv = 0;
    if (row0 + r < N_NODES) wv = cnt_nt[(size_t)(row0 + r) * 32 + j];
    sX[r * 64 + 2 * j]     = (float)(wv & 0xFFFFu);
    sX[r * 64 + 2 * j + 1] = (float)(wv >> 16);
  }
  __syncthreads();
  #pragma unroll 1
  for (int k = 0; k < 16; ++k){
    int r = rb + 2 * k;
    float a = 0.f;
    #pragma unroll
    for (int i = 0; i < 64; ++i) a += sX[r * 64 + i] * sW[i * 128 + c];
    acc[k] += a;
  }

  #pragma unroll
  for (int k = 0; k < 16; ++k){
    int r = rb + 2 * k;
    if (row0 + r < N_NODES) xl[(size_t)(row0 + r) * 128 + c] = acc[k];
  }
}

// ---- a_src/a_dst per (node, head) ----
__global__ __launch_bounds__(256) void k_attn_dots(const float* __restrict__ xl,
                                                   const float* __restrict__ as,
                                                   const float* __restrict__ ad,
                                                   float* __restrict__ a_src,
                                                   float* __restrict__ a_dst){
  int i = blockIdx.x * blockDim.x + threadIdx.x;
  if (i >= N_NODES * HEADS) return;
  int h = i & 3, n = i >> 2;
  const float* row = xl + (size_t)n * OC + h * CH;
  float s = 0.f, d = 0.f;
  #pragma unroll
  for (int c = 0; c < CH; ++c){
    float v = row[c];
    s += v * as[h * CH + c];
    d += v * ad[h * CH + c];
  }
  a_src[i] = s; a_dst[i] = d;
}

// ---- fused: online segment-softmax + aggregate + bias + ELU (wave per node) ----
// lane l owns channels (2l, 2l+1); head h = l>>4.
__global__ __launch_bounds__(256) void k_aggregate(const int* __restrict__ row_dst,
                                                   const int* __restrict__ lst_dst,
                                                   const float* __restrict__ a_src,
                                                   const float* __restrict__ a_dst,
                                                   const float* __restrict__ xl,
                                                   const float* __restrict__ bias,
                                                   float* __restrict__ out){
  int n = (blockIdx.x * blockDim.x + threadIdx.x) >> 6;
  if (n >= N_NODES) return;
  int l = threadIdx.x & 63;
  int h = l >> 4;
  const float2* xlf2 = (const float2*)xl;
  float ad = a_dst[n * 4 + h];

  // self loop init
  float m = lrelu(a_src[n * 4 + h] + ad);
  float lsum = 1.f;
  float2 acc = xlf2[(size_t)n * 64 + l];

  int k0 = row_dst[n], k1 = row_dst[n + 1];
  for (int kb = k0; kb < k1; kb += 64){
    int nk = min(64, k1 - kb);
    int sj = (kb + l < k1) ? lst_dst[kb + l] : 0;   // coalesced batch read
    int s_cur = __shfl(sj, 0);
    float2 v_cur = xlf2[(size_t)s_cur * 64 + l];
    float a_cur = a_src[s_cur * 4 + h];
    for (int j = 0; j < nk; ++j){
      int s_nxt = __shfl(sj, (j + 1 < nk) ? j + 1 : j);
      float2 v_nxt = xlf2[(size_t)s_nxt * 64 + l];  // prefetch next
      float a_nxt = a_src[s_nxt * 4 + h];
      float al = lrelu(a_cur + ad);
      float mn = fmaxf(m, al);
      float f = __expf(m - mn);
      float w = __expf(al - mn);
      lsum = lsum * f + w;
      acc.x = acc.x * f + w * v_cur.x;
      acc.y = acc.y * f + w * v_cur.y;
      m = mn;
      v_cur = v_nxt; a_cur = a_nxt;
    }
  }
  float2 b = ((const float2*)bias)[l];
  float r0 = acc.x / lsum + b.x;
  float r1 = acc.y / lsum + b.y;
  float2 o;
  o.x = r0 > 0.f ? r0 : expm1f(r0);
  o.y = r1 > 0.f ? r1 : expm1f(r1);
  ((float2*)out)[(size_t)n * 64 + l] = o;
}

extern "C" void kernel_launch(void* const* d_in, const int* in_sizes, int n_in,
                              void* d_out, int out_size, void* d_ws, size_t ws_size,
                              hipStream_t stream){
  const float* x     = (const float*)d_in[0];
  const int*   ei    = (const int*)d_in[1];   // [2, E]
  const int*   et    = (const int*)d_in[2];   // [E]
  const float* pe    = (const float*)d_in[3];
  const float* W     = (const float*)d_in[4];
  const float* att_s = (const float*)d_in[5];
  const float* att_d = (const float*)d_in[6];
  const float* bias  = (const float*)d_in[7];
  float* out = (float*)d_out;

  // workspace carve-up
  float* xl    = (float*)d_ws;                               // N*128
  float* a_src = xl + (size_t)N_NODES * OC;                  // N*4
  float* a_dst = a_src + (size_t)N_NODES * HEADS;            // N*4
  float* peW   = a_dst + (size_t)N_NODES * HEADS;            // 64*128
  int* cnt_dst = (int*)(peW + 64 * 128);                     // N
  int* row_dst = cnt_dst + N_NODES;                          // N+1
  int* cur_dst = row_dst + (N_NODES + 1);                    // N
  int* bsum    = cur_dst + N_NODES;                          // 32 (pad)
  unsigned* cnt_nt = (unsigned*)(bsum + 32);                 // N*32
  int* lst_dst = (int*)(cnt_nt + (size_t)N_NODES * 32);      // E

  const int B = 256;

  hipMemsetAsync(cnt_dst, 0, N_NODES * sizeof(int), stream);
  hipMemsetAsync(cnt_nt, 0, (size_t)N_NODES * 32 * sizeof(unsigned), stream);
  k_prep<<<1, B, 0, stream>>>(pe, W, peW);
  k_hist2<<<ceil_div(N_EDGES, B), B, 0, stream>>>(ei, et, cnt_dst, cnt_nt);
  k_scan1<<<SCAN_BLOCKS, B, 0, stream>>>(cnt_dst, bsum);
  k_scan2<<<SCAN_BLOCKS, B, 0, stream>>>(cnt_dst, bsum, row_dst, cur_dst);
  k_scatter_dst<<<ceil_div(N_EDGES, B), B, 0, stream>>>(ei, cur_dst, lst_dst);
  k_gemm_fused<<<ceil_div(N_NODES, GROWS), B, 0, stream>>>(x, cnt_nt, W, peW, xl);
  k_attn_dots<<<ceil_div(N_NODES * HEADS, B), B, 0, stream>>>(xl, att_s, att_d, a_src, a_dst);
  k_aggregate<<<ceil_div(N_NODES * 64, B), B, 0, stream>>>(row_dst, lst_dst, a_src, a_dst, xl, bias, out);
}